// Round 3
// baseline (433.455 us; speedup 1.0000x reference)
//
#include <hip/hip_runtime.h>

// VectorQuantizer: N=131072 tokens, D=64, K=1024 codes.
// out (f32 concat): [0,8388608) quant, [8388608] loss, [8388609,...) idx.
//
// R13: occupancy x2 + launch fusion.
// R12 post-mortem: barrier-free reg-streamed B == R10's 69us exactly, with
// Occupancy 17% (2 waves/SIMD, grid-capped: 512 blocks x 4 waves). Neither
// pipe >34% busy -> latency-bound; 2 waves/SIMD can't cover each other's
// L2/acc-readout stalls. Also ~70us of the 138.7 total is launch overhead
// (3 launches @ ~23us).
// R13:
//  - 128-thread blocks (2 waves x 64 tokens), grid 1024, launch_bounds(128,4)
//    -> 8 blocks/CU = 4 waves/SIMD. Same per-wave structure, same VGPR (~92),
//    same 512MB B-fragment L2 traffic. Pure wave-parallelism doubling.
//  - vq_finish eliminated: per-block loss partial atomicAdd'ed (scaled by
//    exact f32 constant 1.25/2^23) into out[LOSS_OFF], zeroed by vq_setup
//    (stream-ordered). 2 launches instead of 3. Atomic order perturbs loss
//    by ~1e-6 << 4.9e-4 envelope.
// Distance math bit-identical to R4-R12: fp16 split-product MFMA
// (hi*hi+hi*lo+lo*hi) in the same per-accumulator order, np8 x2/e2,
// s=fma(-2,dot,x2+e2), ascending-k strict-< first-min, butterfly epilogue,
// bitwise quant copy.

#define KC 1024
#define DD 64
#define NTOK (32 * 4096)
#define QUANT_ELEMS ((size_t)NTOK * DD)        // 8388608
#define LOSS_OFF QUANT_ELEMS
#define IDX_OFF (QUANT_ELEMS + 1)

// ws float-word offsets (layout identical to R10/R12)
#define WS_E2 0                      // 1024 f32
#define WS_BFRAG_F 2048              // 16384 f16x8 = 65536 f32 words

#define MAIN_BLOCKS (NTOK / 128)     // 1024 blocks, 128 tokens each

typedef _Float16 f16x8 __attribute__((ext_vector_type(8)));
typedef float f32x4 __attribute__((ext_vector_type(4)));

__device__ __forceinline__ unsigned int sortable_bits(float f) {
  unsigned int b = __float_as_uint(f);
  return b ^ (unsigned int)(((int)b >> 31) | 0x80000000);
}

__device__ __forceinline__ float unsortable_bits(unsigned int u) {
  unsigned int fb = (u & 0x80000000u) ? (u ^ 0x80000000u) : ~u;
  return __uint_as_float(fb);
}

// np pairwise-8 sum of squares of a 64-float row (bit-identical to R10)
__device__ __forceinline__ float row_sumsq_np8(const float* p) {
  float r[8];
#pragma unroll
  for (int j = 0; j < 8; ++j) r[j] = p[j] * p[j];
#pragma unroll
  for (int i = 1; i < 8; ++i)
#pragma unroll
    for (int j = 0; j < 8; ++j) {
      float v = p[i * 8 + j];
      r[j] += v * v;
    }
  return ((r[0] + r[1]) + (r[2] + r[3])) + ((r[4] + r[5]) + (r[6] + r[7]));
}

// blocks [0,64): B-frag build; [64,68): e2 table (verbatim R10/R12)
// + block 64 tid 0 zeroes the loss accumulator for this iteration.
__global__ void vq_setup(const float* __restrict__ emb,
                         float* __restrict__ ws,
                         float* __restrict__ out) {
  const int b = blockIdx.x;
  const int tid = threadIdx.x;
  if (b < 64) {
    const int nt = b;                  // global tile 0..63 (16 codes each)
    const int f = tid >> 6;            // 0..3: plane(hi/lo) x kstep
    const int lane = tid & 63;
    const int plane = f >> 1, ks = f & 1;
    const int n = nt * 16 + (lane & 15);
    const int kb = ks * 32 + ((lane >> 4) & 3) * 8;
    const float* ep = emb + (size_t)n * DD + kb;
    f16x8 o;
#pragma unroll
    for (int j = 0; j < 8; ++j) {
      float v = ep[j];
      _Float16 h = (_Float16)v;
      o[j] = (plane == 0) ? h : (_Float16)(v - (float)h);
    }
    ((f16x8*)(ws + WS_BFRAG_F))[(nt * 4 + f) * 64 + lane] = o;
  } else {
    const int k = (b - 64) * 256 + tid;  // 0..1023
    ws[WS_E2 + k] = row_sumsq_np8(emb + (size_t)k * DD);
    if (b == 64 && tid == 0) out[LOSS_OFF] = 0.0f;
  }
}

__launch_bounds__(128, 4)
__global__ void vq_main(const float* __restrict__ x_in,
                        const float* __restrict__ emb,
                        const float* __restrict__ ws_ro,
                        float* __restrict__ out) {
  const int tid = threadIdx.x;
  const int wave = tid >> 6, lane = tid & 63;
  const int quad = lane >> 4, l16 = lane & 15;
  const int tokBase = blockIdx.x * 128 + wave * 64;  // 64 tokens per wave

  __shared__ float E2s[KC];    // 4 KB
  __shared__ float x2s[128];   // per-block token x2
  __shared__ float wsum[2];

  // Stage e2 table to LDS; x2 for this wave's 64 tokens (one row per lane,
  // bit-identical np8 -- value depends only on row data, not producer lane).
#pragma unroll
  for (int i = 0; i < 8; ++i)
    E2s[i * 128 + tid] = ws_ro[WS_E2 + i * 128 + tid];
  x2s[wave * 64 + lane] = row_sumsq_np8(x_in + (size_t)(tokBase + lane) * DD);

  // A fragments: 4 m-sets of 16 tokens; x split into fp16 hi/lo planes.
  f16x8 ah[4][2], al[4][2];
#pragma unroll
  for (int ms = 0; ms < 4; ++ms) {
    const float* xr = x_in + (size_t)(tokBase + ms * 16 + l16) * DD;
#pragma unroll
    for (int ks = 0; ks < 2; ++ks) {
      const float4* p4 = (const float4*)(xr + ks * 32 + quad * 8);
      float4 v0 = p4[0], v1 = p4[1];
      float vv[8] = {v0.x, v0.y, v0.z, v0.w, v1.x, v1.y, v1.z, v1.w};
#pragma unroll
      for (int j = 0; j < 8; ++j) {
        _Float16 h = (_Float16)vv[j];
        ah[ms][ks][j] = h;
        al[ms][ks][j] = (_Float16)(vv[j] - (float)h);
      }
    }
  }

  float best[4][4];
  int bidx[4][4];
#pragma unroll
  for (int ms = 0; ms < 4; ++ms)
#pragma unroll
    for (int r = 0; r < 4; ++r) { best[ms][r] = 3.402823466e38f; bidx[ms][r] = 0; }

  __syncthreads();  // E2s + x2s ready -- the ONLY barrier before epilogue

  // x2 for this lane's C rows: token = tokBase + ms*16 + quad*4 + r
  float x2v[4][4];
#pragma unroll
  for (int ms = 0; ms < 4; ++ms)
#pragma unroll
    for (int r = 0; r < 4; ++r)
      x2v[ms][r] = x2s[wave * 64 + ms * 16 + quad * 4 + r];

  const f16x8* bws = (const f16x8*)(ws_ro + WS_BFRAG_F);

  // Per-tile compute: 24 MFMA (6-product chain per ms, order identical to
  // R4-R12, step-major across the 4 independent chains) + first-min update.
  auto compute = [&](int nt, const f16x8 (&bf)[4]) {
    const int ncur = nt * 16 + l16;       // this lane's code column
    const float e2v = E2s[ncur];
    f32x4 acc[4];
#pragma unroll
    for (int ms = 0; ms < 4; ++ms) acc[ms] = (f32x4){0.f, 0.f, 0.f, 0.f};
    __builtin_amdgcn_s_setprio(1);
#pragma unroll
    for (int ms = 0; ms < 4; ++ms)
      acc[ms] = __builtin_amdgcn_mfma_f32_16x16x32_f16(ah[ms][0], bf[0], acc[ms], 0, 0, 0);
#pragma unroll
    for (int ms = 0; ms < 4; ++ms)
      acc[ms] = __builtin_amdgcn_mfma_f32_16x16x32_f16(ah[ms][1], bf[1], acc[ms], 0, 0, 0);
#pragma unroll
    for (int ms = 0; ms < 4; ++ms)
      acc[ms] = __builtin_amdgcn_mfma_f32_16x16x32_f16(al[ms][0], bf[0], acc[ms], 0, 0, 0);
#pragma unroll
    for (int ms = 0; ms < 4; ++ms)
      acc[ms] = __builtin_amdgcn_mfma_f32_16x16x32_f16(al[ms][1], bf[1], acc[ms], 0, 0, 0);
#pragma unroll
    for (int ms = 0; ms < 4; ++ms)
      acc[ms] = __builtin_amdgcn_mfma_f32_16x16x32_f16(ah[ms][0], bf[2], acc[ms], 0, 0, 0);
#pragma unroll
    for (int ms = 0; ms < 4; ++ms)
      acc[ms] = __builtin_amdgcn_mfma_f32_16x16x32_f16(ah[ms][1], bf[3], acc[ms], 0, 0, 0);
    __builtin_amdgcn_s_setprio(0);
#pragma unroll
    for (int ms = 0; ms < 4; ++ms)
#pragma unroll
      for (int r = 0; r < 4; ++r) {
        float s = __builtin_fmaf(-2.0f, acc[ms][r], x2v[ms][r] + e2v);
        if (s < best[ms][r]) { best[ms][r] = s; bidx[ms][r] = ncur; }
      }
  };

  // Barrier-free main loop: 64 code-tiles, 1-deep register prefetch.
  f16x8 bA[4], bB[4];
#pragma unroll
  for (int i = 0; i < 4; ++i) bA[i] = bws[i * 64 + lane];

  for (int nt = 0; nt < 64; nt += 2) {
#pragma unroll
    for (int i = 0; i < 4; ++i) bB[i] = bws[((nt + 1) * 4 + i) * 64 + lane];
    compute(nt, bA);
    if (nt + 2 < 64) {
#pragma unroll
      for (int i = 0; i < 4; ++i) bA[i] = bws[((nt + 2) * 4 + i) * 64 + lane];
    }
    compute(nt + 1, bB);
  }

  // Butterfly min across each quad's 16 lanes -> ALL lanes hold the winner.
  unsigned long long key[4][4];
#pragma unroll
  for (int ms = 0; ms < 4; ++ms)
#pragma unroll
    for (int r = 0; r < 4; ++r) {
      unsigned long long k =
          ((unsigned long long)sortable_bits(best[ms][r]) << 32) |
          (unsigned int)bidx[ms][r];
#pragma unroll
      for (int m = 1; m < 16; m <<= 1) {
        unsigned long long o = __shfl_xor(k, m);
        k = o < k ? o : k;
      }
      key[ms][r] = k;
    }

  // Fused epilogue: idx store (quad lane 0), quant gather+store (all lanes),
  // loss partial decoded from keys.
  float qsum = 0.0f;
#pragma unroll
  for (int ms = 0; ms < 4; ++ms)
#pragma unroll
    for (int r = 0; r < 4; ++r) {
      const int token = tokBase + ms * 16 + quad * 4 + r;
      const int widx = (int)(unsigned int)key[ms][r];
      if (l16 == 0) out[IDX_OFF + (size_t)token] = (float)widx;
      // 16 lanes x float4 = the winning 256B row, bitwise copy
      const float4 v = ((const float4*)(emb + (size_t)widx * DD))[l16];
      ((float4*)(out + (size_t)token * DD))[l16] = v;
      qsum += unsortable_bits((unsigned int)(key[ms][r] >> 32));
    }

  // qsum identical across a quad's 16 lanes; sum the 4 quads, then 2 waves,
  // then atomicAdd the scaled partial into the loss cell (zeroed by setup).
  float tot = __shfl(qsum, 0) + __shfl(qsum, 16) +
              __shfl(qsum, 32) + __shfl(qsum, 48);
  if (lane == 0) wsum[wave] = tot;
  __syncthreads();
  if (tid == 0) {
    // 1.25f / 2^23 is exactly representable; one rounding per block.
    const float scale = 1.25f / (float)QUANT_ELEMS;
    atomicAdd(&out[LOSS_OFF], (wsum[0] + wsum[1]) * scale);
  }
}

extern "C" void kernel_launch(void* const* d_in, const int* in_sizes, int n_in,
                              void* d_out, int out_size, void* d_ws, size_t ws_size,
                              hipStream_t stream) {
  const float* x = (const float*)d_in[0];
  const float* emb = (const float*)d_in[1];
  float* out = (float*)d_out;
  float* ws = (float*)d_ws;

  vq_setup<<<68, 256, 0, stream>>>(emb, ws, out);
  vq_main<<<MAIN_BLOCKS, 128, 0, stream>>>(x, emb, ws, out);
}

// Round 4
// 136.351 us; speedup vs baseline: 3.1790x; 3.1790x over previous
//
#include <hip/hip_runtime.h>

// VectorQuantizer: N=131072 tokens, D=64, K=1024 codes.
// out (f32 concat): [0,8388608) quant, [8388608] loss, [8388609,...) idx.
//
// R14: occupancy x2 done right.
// R13 post-mortem: __launch_bounds__(128,4) capped VGPR at 64; A-fragments
// alone need 64 -> compiler rematerialized them by RE-LOADING x every tile
// (FETCH 18.7MB -> 960MB, MfmaUtil 5.6%). The occupancy idea was never
// actually tested. Lesson: min-waves bound is for the allocator; residency
// comes from actual VGPR/LDS.
// R14:
//  - 32 tokens/wave (2 m-sets) -> 4096 total waves = 16 waves/CU = 4/SIMD,
//    the real occupancy doubling R13 aimed for. B-fragment L2 traffic
//    doubles to ~1GB (~20 TB/s aggregate, under the 34.5 TB/s L2 ceiling);
//    HBM traffic unchanged.
//  - grid 1024 x 256 threads, __launch_bounds__(256,2) -- the PROVEN R12
//    bound (92 VGPR). Per-wave state is smaller here (~70-90 VGPR), so the
//    HW will co-resident 4 blocks/CU by itself.
//  - keeps R13's verified loss fusion: per-block partial atomicAdd'ed
//    (exact f32 scale 1.25/2^23) into out[LOSS_OFF], zeroed by setup.
//    2 launches.
// Distance math bit-identical to R4-R13: fp16 split-product MFMA
// (hi*hi+hi*lo+lo*hi) in the same per-accumulator order, np8 x2/e2,
// s=fma(-2,dot,x2+e2), ascending-k strict-< first-min, butterfly epilogue,
// bitwise quant copy. Token->wave remap cannot change per-token results.

#define KC 1024
#define DD 64
#define NTOK (32 * 4096)
#define QUANT_ELEMS ((size_t)NTOK * DD)        // 8388608
#define LOSS_OFF QUANT_ELEMS
#define IDX_OFF (QUANT_ELEMS + 1)

// ws float-word offsets (layout identical to R10/R12)
#define WS_E2 0                      // 1024 f32
#define WS_BFRAG_F 2048              // 16384 f16x8 = 65536 f32 words

#define MAIN_BLOCKS (NTOK / 128)     // 1024 blocks, 128 tokens each

typedef _Float16 f16x8 __attribute__((ext_vector_type(8)));
typedef float f32x4 __attribute__((ext_vector_type(4)));

__device__ __forceinline__ unsigned int sortable_bits(float f) {
  unsigned int b = __float_as_uint(f);
  return b ^ (unsigned int)(((int)b >> 31) | 0x80000000);
}

__device__ __forceinline__ float unsortable_bits(unsigned int u) {
  unsigned int fb = (u & 0x80000000u) ? (u ^ 0x80000000u) : ~u;
  return __uint_as_float(fb);
}

// np pairwise-8 sum of squares of a 64-float row (bit-identical to R10)
__device__ __forceinline__ float row_sumsq_np8(const float* p) {
  float r[8];
#pragma unroll
  for (int j = 0; j < 8; ++j) r[j] = p[j] * p[j];
#pragma unroll
  for (int i = 1; i < 8; ++i)
#pragma unroll
    for (int j = 0; j < 8; ++j) {
      float v = p[i * 8 + j];
      r[j] += v * v;
    }
  return ((r[0] + r[1]) + (r[2] + r[3])) + ((r[4] + r[5]) + (r[6] + r[7]));
}

// blocks [0,64): B-frag build; [64,68): e2 table (verbatim R10/R12)
// + block 64 tid 0 zeroes the loss accumulator for this iteration.
__global__ void vq_setup(const float* __restrict__ emb,
                         float* __restrict__ ws,
                         float* __restrict__ out) {
  const int b = blockIdx.x;
  const int tid = threadIdx.x;
  if (b < 64) {
    const int nt = b;                  // global tile 0..63 (16 codes each)
    const int f = tid >> 6;            // 0..3: plane(hi/lo) x kstep
    const int lane = tid & 63;
    const int plane = f >> 1, ks = f & 1;
    const int n = nt * 16 + (lane & 15);
    const int kb = ks * 32 + ((lane >> 4) & 3) * 8;
    const float* ep = emb + (size_t)n * DD + kb;
    f16x8 o;
#pragma unroll
    for (int j = 0; j < 8; ++j) {
      float v = ep[j];
      _Float16 h = (_Float16)v;
      o[j] = (plane == 0) ? h : (_Float16)(v - (float)h);
    }
    ((f16x8*)(ws + WS_BFRAG_F))[(nt * 4 + f) * 64 + lane] = o;
  } else {
    const int k = (b - 64) * 256 + tid;  // 0..1023
    ws[WS_E2 + k] = row_sumsq_np8(emb + (size_t)k * DD);
    if (b == 64 && tid == 0) out[LOSS_OFF] = 0.0f;
  }
}

__launch_bounds__(256, 2)
__global__ void vq_main(const float* __restrict__ x_in,
                        const float* __restrict__ emb,
                        const float* __restrict__ ws_ro,
                        float* __restrict__ out) {
  const int tid = threadIdx.x;
  const int wave = tid >> 6, lane = tid & 63;
  const int quad = lane >> 4, l16 = lane & 15;
  const int blockTok = blockIdx.x * 128;
  const int tokBase = blockTok + wave * 32;  // 32 tokens per wave

  __shared__ float E2s[KC];    // 4 KB
  __shared__ float x2s[128];   // per-block token x2
  __shared__ float wsum[4];

  // Stage e2 table to LDS; x2: one row per thread for tid<128
  // (bit-identical np8 -- value depends only on row data, not producer).
#pragma unroll
  for (int i = 0; i < 4; ++i)
    E2s[i * 256 + tid] = ws_ro[WS_E2 + i * 256 + tid];
  if (tid < 128)
    x2s[tid] = row_sumsq_np8(x_in + (size_t)(blockTok + tid) * DD);

  // A fragments: 2 m-sets of 16 tokens; x split into fp16 hi/lo planes.
  f16x8 ah[2][2], al[2][2];
#pragma unroll
  for (int ms = 0; ms < 2; ++ms) {
    const float* xr = x_in + (size_t)(tokBase + ms * 16 + l16) * DD;
#pragma unroll
    for (int ks = 0; ks < 2; ++ks) {
      const float4* p4 = (const float4*)(xr + ks * 32 + quad * 8);
      float4 v0 = p4[0], v1 = p4[1];
      float vv[8] = {v0.x, v0.y, v0.z, v0.w, v1.x, v1.y, v1.z, v1.w};
#pragma unroll
      for (int j = 0; j < 8; ++j) {
        _Float16 h = (_Float16)vv[j];
        ah[ms][ks][j] = h;
        al[ms][ks][j] = (_Float16)(vv[j] - (float)h);
      }
    }
  }

  float best[2][4];
  int bidx[2][4];
#pragma unroll
  for (int ms = 0; ms < 2; ++ms)
#pragma unroll
    for (int r = 0; r < 4; ++r) { best[ms][r] = 3.402823466e38f; bidx[ms][r] = 0; }

  __syncthreads();  // E2s + x2s ready -- the ONLY barrier before epilogue

  // x2 for this lane's C rows: token = tokBase + ms*16 + quad*4 + r
  float x2v[2][4];
#pragma unroll
  for (int ms = 0; ms < 2; ++ms)
#pragma unroll
    for (int r = 0; r < 4; ++r)
      x2v[ms][r] = x2s[wave * 32 + ms * 16 + quad * 4 + r];

  const f16x8* bws = (const f16x8*)(ws_ro + WS_BFRAG_F);

  // Per-tile compute: 12 MFMA (6-product chain per ms, order identical to
  // R4-R13, step-major across the 2 independent chains) + first-min update.
  auto compute = [&](int nt, const f16x8 (&bf)[4]) {
    const int ncur = nt * 16 + l16;       // this lane's code column
    const float e2v = E2s[ncur];
    f32x4 acc[2];
#pragma unroll
    for (int ms = 0; ms < 2; ++ms) acc[ms] = (f32x4){0.f, 0.f, 0.f, 0.f};
    __builtin_amdgcn_s_setprio(1);
#pragma unroll
    for (int ms = 0; ms < 2; ++ms)
      acc[ms] = __builtin_amdgcn_mfma_f32_16x16x32_f16(ah[ms][0], bf[0], acc[ms], 0, 0, 0);
#pragma unroll
    for (int ms = 0; ms < 2; ++ms)
      acc[ms] = __builtin_amdgcn_mfma_f32_16x16x32_f16(ah[ms][1], bf[1], acc[ms], 0, 0, 0);
#pragma unroll
    for (int ms = 0; ms < 2; ++ms)
      acc[ms] = __builtin_amdgcn_mfma_f32_16x16x32_f16(al[ms][0], bf[0], acc[ms], 0, 0, 0);
#pragma unroll
    for (int ms = 0; ms < 2; ++ms)
      acc[ms] = __builtin_amdgcn_mfma_f32_16x16x32_f16(al[ms][1], bf[1], acc[ms], 0, 0, 0);
#pragma unroll
    for (int ms = 0; ms < 2; ++ms)
      acc[ms] = __builtin_amdgcn_mfma_f32_16x16x32_f16(ah[ms][0], bf[2], acc[ms], 0, 0, 0);
#pragma unroll
    for (int ms = 0; ms < 2; ++ms)
      acc[ms] = __builtin_amdgcn_mfma_f32_16x16x32_f16(ah[ms][1], bf[3], acc[ms], 0, 0, 0);
    __builtin_amdgcn_s_setprio(0);
#pragma unroll
    for (int ms = 0; ms < 2; ++ms)
#pragma unroll
      for (int r = 0; r < 4; ++r) {
        float s = __builtin_fmaf(-2.0f, acc[ms][r], x2v[ms][r] + e2v);
        if (s < best[ms][r]) { best[ms][r] = s; bidx[ms][r] = ncur; }
      }
  };

  // Barrier-free main loop: 64 code-tiles, 1-deep register prefetch.
  f16x8 bA[4], bB[4];
#pragma unroll
  for (int i = 0; i < 4; ++i) bA[i] = bws[i * 64 + lane];

  for (int nt = 0; nt < 64; nt += 2) {
#pragma unroll
    for (int i = 0; i < 4; ++i) bB[i] = bws[((nt + 1) * 4 + i) * 64 + lane];
    compute(nt, bA);
    if (nt + 2 < 64) {
#pragma unroll
      for (int i = 0; i < 4; ++i) bA[i] = bws[((nt + 2) * 4 + i) * 64 + lane];
    }
    compute(nt + 1, bB);
  }

  // Butterfly min across each quad's 16 lanes -> ALL lanes hold the winner.
  unsigned long long key[2][4];
#pragma unroll
  for (int ms = 0; ms < 2; ++ms)
#pragma unroll
    for (int r = 0; r < 4; ++r) {
      unsigned long long k =
          ((unsigned long long)sortable_bits(best[ms][r]) << 32) |
          (unsigned int)bidx[ms][r];
#pragma unroll
      for (int m = 1; m < 16; m <<= 1) {
        unsigned long long o = __shfl_xor(k, m);
        k = o < k ? o : k;
      }
      key[ms][r] = k;
    }

  // Fused epilogue: idx store (quad lane 0), quant gather+store (all lanes),
  // loss partial decoded from keys.
  float qsum = 0.0f;
#pragma unroll
  for (int ms = 0; ms < 2; ++ms)
#pragma unroll
    for (int r = 0; r < 4; ++r) {
      const int token = tokBase + ms * 16 + quad * 4 + r;
      const int widx = (int)(unsigned int)key[ms][r];
      if (l16 == 0) out[IDX_OFF + (size_t)token] = (float)widx;
      // 16 lanes x float4 = the winning 256B row, bitwise copy
      const float4 v = ((const float4*)(emb + (size_t)widx * DD))[l16];
      ((float4*)(out + (size_t)token * DD))[l16] = v;
      qsum += unsortable_bits((unsigned int)(key[ms][r] >> 32));
    }

  // qsum identical across a quad's 16 lanes; sum the 4 quads, then 4 waves,
  // then atomicAdd the scaled partial into the loss cell (zeroed by setup).
  float tot = __shfl(qsum, 0) + __shfl(qsum, 16) +
              __shfl(qsum, 32) + __shfl(qsum, 48);
  if (lane == 0) wsum[wave] = tot;
  __syncthreads();
  if (tid == 0) {
    // 1.25f / 2^23 is exactly representable; one rounding per block.
    const float scale = 1.25f / (float)QUANT_ELEMS;
    atomicAdd(&out[LOSS_OFF], ((wsum[0] + wsum[1]) + (wsum[2] + wsum[3])) * scale);
  }
}

extern "C" void kernel_launch(void* const* d_in, const int* in_sizes, int n_in,
                              void* d_out, int out_size, void* d_ws, size_t ws_size,
                              hipStream_t stream) {
  const float* x = (const float*)d_in[0];
  const float* emb = (const float*)d_in[1];
  float* out = (float*)d_out;
  float* ws = (float*)d_ws;

  vq_setup<<<68, 256, 0, stream>>>(emb, ws, out);
  vq_main<<<MAIN_BLOCKS, 256, 0, stream>>>(x, emb, ws, out);
}

// Round 5
// 134.854 us; speedup vs baseline: 3.2143x; 1.0111x over previous
//
#include <hip/hip_runtime.h>

// VectorQuantizer: N=131072 tokens, D=64, K=1024 codes.
// out (f32 concat): [0,8388608) quant, [8388608] loss, [8388609,...) idx.
//
// R15: deep register prefetch, no setprio.
// R14 post-mortem: occupancy 17->31% with HALVED per-wave tile work gave
// ZERO speedup -> stall is prefetch-depth-limited, not TLP-limited. 1-deep
// prefetch covers one compute phase (~230-460 cyc) vs contended L2 latency
// (~300-500 cyc); halving the phase (R14) exactly cancelled the doubled TLP.
// Also: setprio(1) in a lockstep-uniform loop is the measured-negative
// regime (m190); and 32 tok/wave doubled B-frag L2 traffic to ~1GB (~31us
// L2-BW floor).
// R15:
//  - back to 64 tokens/wave (4 m-sets): B-frag L2 traffic 0.53GB (~15us
//    floor), proven R12 shape under __launch_bounds__(256,2).
//  - 4-deep NAMED prefetch buffers b0..b3 (static indexing only, rule #20):
//    load tile nt+4 right after compute(nt) frees its buffer -> ~3 compute
//    phases (~1400 cyc) of latency cover; compiler emits counted vmcnt.
//  - s_setprio REMOVED.
//  - keeps R13/R14 loss fusion: per-block partial atomicAdd'ed (exact f32
//    scale 1.25/2^23) into out[LOSS_OFF], zeroed by setup. 2 launches.
// Distance math bit-identical to R4-R14: fp16 split-product MFMA
// (hi*hi+hi*lo+lo*hi) in the same per-accumulator order, np8 x2/e2,
// s=fma(-2,dot,x2+e2), ascending-k strict-< first-min, butterfly epilogue,
// bitwise quant copy.

#define KC 1024
#define DD 64
#define NTOK (32 * 4096)
#define QUANT_ELEMS ((size_t)NTOK * DD)        // 8388608
#define LOSS_OFF QUANT_ELEMS
#define IDX_OFF (QUANT_ELEMS + 1)

// ws float-word offsets (layout identical to R10/R12)
#define WS_E2 0                      // 1024 f32
#define WS_BFRAG_F 2048              // 16384 f16x8 = 65536 f32 words

#define MAIN_BLOCKS (NTOK / 256)     // 512 blocks, 256 tokens each

typedef _Float16 f16x8 __attribute__((ext_vector_type(8)));
typedef float f32x4 __attribute__((ext_vector_type(4)));

__device__ __forceinline__ unsigned int sortable_bits(float f) {
  unsigned int b = __float_as_uint(f);
  return b ^ (unsigned int)(((int)b >> 31) | 0x80000000);
}

__device__ __forceinline__ float unsortable_bits(unsigned int u) {
  unsigned int fb = (u & 0x80000000u) ? (u ^ 0x80000000u) : ~u;
  return __uint_as_float(fb);
}

// np pairwise-8 sum of squares of a 64-float row (bit-identical to R10)
__device__ __forceinline__ float row_sumsq_np8(const float* p) {
  float r[8];
#pragma unroll
  for (int j = 0; j < 8; ++j) r[j] = p[j] * p[j];
#pragma unroll
  for (int i = 1; i < 8; ++i)
#pragma unroll
    for (int j = 0; j < 8; ++j) {
      float v = p[i * 8 + j];
      r[j] += v * v;
    }
  return ((r[0] + r[1]) + (r[2] + r[3])) + ((r[4] + r[5]) + (r[6] + r[7]));
}

// blocks [0,64): B-frag build; [64,68): e2 table (verbatim R10/R12)
// + block 64 tid 0 zeroes the loss accumulator for this iteration.
__global__ void vq_setup(const float* __restrict__ emb,
                         float* __restrict__ ws,
                         float* __restrict__ out) {
  const int b = blockIdx.x;
  const int tid = threadIdx.x;
  if (b < 64) {
    const int nt = b;                  // global tile 0..63 (16 codes each)
    const int f = tid >> 6;            // 0..3: plane(hi/lo) x kstep
    const int lane = tid & 63;
    const int plane = f >> 1, ks = f & 1;
    const int n = nt * 16 + (lane & 15);
    const int kb = ks * 32 + ((lane >> 4) & 3) * 8;
    const float* ep = emb + (size_t)n * DD + kb;
    f16x8 o;
#pragma unroll
    for (int j = 0; j < 8; ++j) {
      float v = ep[j];
      _Float16 h = (_Float16)v;
      o[j] = (plane == 0) ? h : (_Float16)(v - (float)h);
    }
    ((f16x8*)(ws + WS_BFRAG_F))[(nt * 4 + f) * 64 + lane] = o;
  } else {
    const int k = (b - 64) * 256 + tid;  // 0..1023
    ws[WS_E2 + k] = row_sumsq_np8(emb + (size_t)k * DD);
    if (b == 64 && tid == 0) out[LOSS_OFF] = 0.0f;
  }
}

__launch_bounds__(256, 2)
__global__ void vq_main(const float* __restrict__ x_in,
                        const float* __restrict__ emb,
                        const float* __restrict__ ws_ro,
                        float* __restrict__ out) {
  const int tid = threadIdx.x;
  const int wave = tid >> 6, lane = tid & 63;
  const int quad = lane >> 4, l16 = lane & 15;
  const int tokBase = blockIdx.x * 256 + wave * 64;  // 64 tokens per wave

  __shared__ float E2s[KC];    // 4 KB
  __shared__ float x2s[256];   // per-block token x2
  __shared__ float wsum[4];

  // Stage e2 table to LDS; x2 for this wave's 64 tokens (one row per lane,
  // bit-identical np8 -- value depends only on row data, not producer lane).
#pragma unroll
  for (int i = 0; i < 4; ++i)
    E2s[i * 256 + tid] = ws_ro[WS_E2 + i * 256 + tid];
  x2s[wave * 64 + lane] = row_sumsq_np8(x_in + (size_t)(tokBase + lane) * DD);

  // A fragments: 4 m-sets of 16 tokens; x split into fp16 hi/lo planes.
  f16x8 ah[4][2], al[4][2];
#pragma unroll
  for (int ms = 0; ms < 4; ++ms) {
    const float* xr = x_in + (size_t)(tokBase + ms * 16 + l16) * DD;
#pragma unroll
    for (int ks = 0; ks < 2; ++ks) {
      const float4* p4 = (const float4*)(xr + ks * 32 + quad * 8);
      float4 v0 = p4[0], v1 = p4[1];
      float vv[8] = {v0.x, v0.y, v0.z, v0.w, v1.x, v1.y, v1.z, v1.w};
#pragma unroll
      for (int j = 0; j < 8; ++j) {
        _Float16 h = (_Float16)vv[j];
        ah[ms][ks][j] = h;
        al[ms][ks][j] = (_Float16)(vv[j] - (float)h);
      }
    }
  }

  float best[4][4];
  int bidx[4][4];
#pragma unroll
  for (int ms = 0; ms < 4; ++ms)
#pragma unroll
    for (int r = 0; r < 4; ++r) { best[ms][r] = 3.402823466e38f; bidx[ms][r] = 0; }

  __syncthreads();  // E2s + x2s ready -- the ONLY barrier before epilogue

  // x2 for this lane's C rows: token = tokBase + ms*16 + quad*4 + r
  float x2v[4][4];
#pragma unroll
  for (int ms = 0; ms < 4; ++ms)
#pragma unroll
    for (int r = 0; r < 4; ++r)
      x2v[ms][r] = x2s[wave * 64 + ms * 16 + quad * 4 + r];

  const f16x8* bws = (const f16x8*)(ws_ro + WS_BFRAG_F);

  // Per-tile compute: 24 MFMA (6-product chain per ms, order identical to
  // R4-R14, step-major across the 4 independent chains) + first-min update.
  auto compute = [&](int nt, const f16x8 (&bf)[4]) {
    const int ncur = nt * 16 + l16;       // this lane's code column
    const float e2v = E2s[ncur];
    f32x4 acc[4];
#pragma unroll
    for (int ms = 0; ms < 4; ++ms) acc[ms] = (f32x4){0.f, 0.f, 0.f, 0.f};
#pragma unroll
    for (int ms = 0; ms < 4; ++ms)
      acc[ms] = __builtin_amdgcn_mfma_f32_16x16x32_f16(ah[ms][0], bf[0], acc[ms], 0, 0, 0);
#pragma unroll
    for (int ms = 0; ms < 4; ++ms)
      acc[ms] = __builtin_amdgcn_mfma_f32_16x16x32_f16(ah[ms][1], bf[1], acc[ms], 0, 0, 0);
#pragma unroll
    for (int ms = 0; ms < 4; ++ms)
      acc[ms] = __builtin_amdgcn_mfma_f32_16x16x32_f16(al[ms][0], bf[0], acc[ms], 0, 0, 0);
#pragma unroll
    for (int ms = 0; ms < 4; ++ms)
      acc[ms] = __builtin_amdgcn_mfma_f32_16x16x32_f16(al[ms][1], bf[1], acc[ms], 0, 0, 0);
#pragma unroll
    for (int ms = 0; ms < 4; ++ms)
      acc[ms] = __builtin_amdgcn_mfma_f32_16x16x32_f16(ah[ms][0], bf[2], acc[ms], 0, 0, 0);
#pragma unroll
    for (int ms = 0; ms < 4; ++ms)
      acc[ms] = __builtin_amdgcn_mfma_f32_16x16x32_f16(ah[ms][1], bf[3], acc[ms], 0, 0, 0);
#pragma unroll
    for (int ms = 0; ms < 4; ++ms)
#pragma unroll
      for (int r = 0; r < 4; ++r) {
        float s = __builtin_fmaf(-2.0f, acc[ms][r], x2v[ms][r] + e2v);
        if (s < best[ms][r]) { best[ms][r] = s; bidx[ms][r] = ncur; }
      }
  };

  // Barrier-free main loop: 64 code-tiles, 4-deep named register prefetch.
  f16x8 b0[4], b1[4], b2[4], b3[4];
#pragma unroll
  for (int i = 0; i < 4; ++i) b0[i] = bws[(0 * 4 + i) * 64 + lane];
#pragma unroll
  for (int i = 0; i < 4; ++i) b1[i] = bws[(1 * 4 + i) * 64 + lane];
#pragma unroll
  for (int i = 0; i < 4; ++i) b2[i] = bws[(2 * 4 + i) * 64 + lane];
#pragma unroll
  for (int i = 0; i < 4; ++i) b3[i] = bws[(3 * 4 + i) * 64 + lane];

  for (int nt = 0; nt < 60; nt += 4) {
    compute(nt + 0, b0);
#pragma unroll
    for (int i = 0; i < 4; ++i) b0[i] = bws[((nt + 4) * 4 + i) * 64 + lane];
    compute(nt + 1, b1);
#pragma unroll
    for (int i = 0; i < 4; ++i) b1[i] = bws[((nt + 5) * 4 + i) * 64 + lane];
    compute(nt + 2, b2);
#pragma unroll
    for (int i = 0; i < 4; ++i) b2[i] = bws[((nt + 6) * 4 + i) * 64 + lane];
    compute(nt + 3, b3);
#pragma unroll
    for (int i = 0; i < 4; ++i) b3[i] = bws[((nt + 7) * 4 + i) * 64 + lane];
  }
  compute(60, b0);
  compute(61, b1);
  compute(62, b2);
  compute(63, b3);

  // Butterfly min across each quad's 16 lanes -> ALL lanes hold the winner.
  unsigned long long key[4][4];
#pragma unroll
  for (int ms = 0; ms < 4; ++ms)
#pragma unroll
    for (int r = 0; r < 4; ++r) {
      unsigned long long k =
          ((unsigned long long)sortable_bits(best[ms][r]) << 32) |
          (unsigned int)bidx[ms][r];
#pragma unroll
      for (int m = 1; m < 16; m <<= 1) {
        unsigned long long o = __shfl_xor(k, m);
        k = o < k ? o : k;
      }
      key[ms][r] = k;
    }

  // Fused epilogue: idx store (quad lane 0), quant gather+store (all lanes),
  // loss partial decoded from keys.
  float qsum = 0.0f;
#pragma unroll
  for (int ms = 0; ms < 4; ++ms)
#pragma unroll
    for (int r = 0; r < 4; ++r) {
      const int token = tokBase + ms * 16 + quad * 4 + r;
      const int widx = (int)(unsigned int)key[ms][r];
      if (l16 == 0) out[IDX_OFF + (size_t)token] = (float)widx;
      // 16 lanes x float4 = the winning 256B row, bitwise copy
      const float4 v = ((const float4*)(emb + (size_t)widx * DD))[l16];
      ((float4*)(out + (size_t)token * DD))[l16] = v;
      qsum += unsortable_bits((unsigned int)(key[ms][r] >> 32));
    }

  // qsum identical across a quad's 16 lanes; sum the 4 quads, then 4 waves,
  // then atomicAdd the scaled partial into the loss cell (zeroed by setup).
  float tot = __shfl(qsum, 0) + __shfl(qsum, 16) +
              __shfl(qsum, 32) + __shfl(qsum, 48);
  if (lane == 0) wsum[wave] = tot;
  __syncthreads();
  if (tid == 0) {
    // 1.25f / 2^23 is exactly representable; one rounding per block.
    const float scale = 1.25f / (float)QUANT_ELEMS;
    atomicAdd(&out[LOSS_OFF], ((wsum[0] + wsum[1]) + (wsum[2] + wsum[3])) * scale);
  }
}

extern "C" void kernel_launch(void* const* d_in, const int* in_sizes, int n_in,
                              void* d_out, int out_size, void* d_ws, size_t ws_size,
                              hipStream_t stream) {
  const float* x = (const float*)d_in[0];
  const float* emb = (const float*)d_in[1];
  float* out = (float*)d_out;
  float* ws = (float*)d_ws;

  vq_setup<<<68, 256, 0, stream>>>(emb, ws, out);
  vq_main<<<MAIN_BLOCKS, 256, 0, stream>>>(x, emb, ws, out);
}